// Round 1
// baseline (84.754 us; speedup 1.0000x reference)
//
#include <hip/hip_runtime.h>

#define BG_OPACITY 1.0e10f
#define EPS_RM 1e-6f

// Layout (all float32):
//   d_in[0] rays_densities : (BR, 64)      BR = B*R = 262144
//   d_in[1] rays_features  : (BR, 64, 3)
//   d_in[2] ray_lengths    : (BR, 64)
//   d_in[3] bg_color       : (1,)
// d_out = [features (BR,3) | depth (BR,1) | opacities (BR,1) | weights (BR,64)]
//
// Key simplification (SURFACE_THICKNESS=1, s=-1 in the reference):
//   sc = [1]*(N-1) ++ [c[0]]  ->  absorption = [c0, 1, 1, ..., 1]
//   c0 = 1+EPS - (1 - exp(-S)) = EPS + exp(-S),  S = sum_j delta_j * relu(rho_j)
// So no per-sample scan is needed, only the per-ray total S.

__global__ __launch_bounds__(256) void raymarch_kernel(
    const float4* __restrict__ dens4,   // (BR * 16) float4
    const float4* __restrict__ feat4,   // (BR * 48) float4
    const float4* __restrict__ len4,    // (BR * 16) float4
    const float*  __restrict__ bgp,     // (1,)
    float*  __restrict__ out_feat,      // (BR*3)
    float*  __restrict__ out_depth,     // (BR)
    float*  __restrict__ out_opac,      // (BR)
    float4* __restrict__ out_w4,        // (BR * 16) float4
    int n_rays)
{
    const int lane   = threadIdx.x & 63;
    const int q      = lane & 15;        // sample-chunk index within ray (16 lanes/ray)
    const int rslot  = lane >> 4;        // which of the 4 rays this wave handles
    const int wid    = (blockIdx.x * blockDim.x + threadIdx.x) >> 6;
    const int nwaves = (gridDim.x * blockDim.x) >> 6;
    const float bg   = bgp[0];

    const int ngroups = (n_rays + 3) >> 2;   // 4 rays per wave

    for (int g = wid; g < ngroups; g += nwaves) {
        const int ray = g * 4 + rslot;
        if (ray >= n_rays) continue;   // whole 16-lane group exits together

        const size_t rbase = (size_t)ray * 16;   // float4 units
        float4 dv = dens4[rbase + q];            // densities, samples 4q..4q+3
        float4 lv = len4[rbase + q];             // lengths,   samples 4q..4q+3

        // deltas: diff within lane; boundary needs next lane's first length
        float nlen = __shfl_down(lv.x, 1);       // q==15 value unused (delta=BG)
        float d0 = lv.y - lv.x;
        float d1 = lv.z - lv.y;
        float d2 = lv.w - lv.z;
        float d3 = (q < 15) ? (nlen - lv.w) : BG_OPACITY;

        float r0 = fmaxf(dv.x, 0.f), r1 = fmaxf(dv.y, 0.f);
        float r2 = fmaxf(dv.z, 0.f), r3 = fmaxf(dv.w, 0.f);
        float w0 = d0 * r0, w1 = d1 * r1, w2 = d2 * r2, w3 = d3 * r3;

        // total optical depth S across the ray (16-lane butterfly, masks < 16)
        float S = (w0 + w1) + (w2 + w3);
        #pragma unroll
        for (int m = 1; m < 16; m <<= 1) S += __shfl_xor(S, m);

        float c0 = 1.f - __expf(-w0);
        float c1 = 1.f - __expf(-w1);
        float c2 = 1.f - __expf(-w2);
        float c3 = 1.f - __expf(-w3);
        if (q == 0) c0 *= (EPS_RM + __expf(-S));   // absorption hits only sample 0

        out_w4[rbase + q] = make_float4(c0, c1, c2, c3);

        // features: per ray 48 float4; lane q owns float4s [3q, 3q+1, 3q+2]
        const size_t fbase = (size_t)ray * 48 + (size_t)q * 3;
        float4 f0 = feat4[fbase + 0];  // s0.x s0.y s0.z s1.x
        float4 f1 = feat4[fbase + 1];  // s1.y s1.z s2.x s2.y
        float4 f2 = feat4[fbase + 2];  // s2.z s3.x s3.y s3.z

        float fx = c0 * f0.x + c1 * f0.w + c2 * f1.z + c3 * f2.y;
        float fy = c0 * f0.y + c1 * f1.x + c2 * f1.w + c3 * f2.z;
        float fz = c0 * f0.z + c1 * f1.y + c2 * f2.x + c3 * f2.w;
        float dp = c0 * lv.x + c1 * lv.y + c2 * lv.z + c3 * lv.w;

        #pragma unroll
        for (int m = 1; m < 16; m <<= 1) {
            fx += __shfl_xor(fx, m);
            fy += __shfl_xor(fy, m);
            fz += __shfl_xor(fz, m);
            dp += __shfl_xor(dp, m);
        }

        if (q == 0) {
            float opac  = 1.f - __expf(-S);
            float addbg = (1.f - opac) * bg;
            out_feat[(size_t)ray * 3 + 0] = fx + addbg;
            out_feat[(size_t)ray * 3 + 1] = fy + addbg;
            out_feat[(size_t)ray * 3 + 2] = fz + addbg;
            out_depth[ray] = dp;
            out_opac[ray]  = opac;
        }
    }
}

extern "C" void kernel_launch(void* const* d_in, const int* in_sizes, int n_in,
                              void* d_out, int out_size, void* d_ws, size_t ws_size,
                              hipStream_t stream) {
    const float4* dens4 = (const float4*)d_in[0];
    const float4* feat4 = (const float4*)d_in[1];
    const float4* len4  = (const float4*)d_in[2];
    const float*  bgp   = (const float*)d_in[3];

    const int n_rays = in_sizes[0] / 64;   // densities: (BR, 64, 1)

    float* out = (float*)d_out;
    float*  out_feat  = out;                          // BR*3
    float*  out_depth = out + (size_t)n_rays * 3;     // BR
    float*  out_opac  = out + (size_t)n_rays * 4;     // BR
    float4* out_w4    = (float4*)(out + (size_t)n_rays * 5);  // BR*64

    const int ngroups = (n_rays + 3) / 4;     // 4 rays per wave
    const int waves_per_block = 256 / 64;
    int blocks = (ngroups + waves_per_block - 1) / waves_per_block;
    if (blocks > 2048) blocks = 2048;
    if (blocks < 1) blocks = 1;

    raymarch_kernel<<<blocks, 256, 0, stream>>>(
        dens4, feat4, len4, bgp,
        out_feat, out_depth, out_opac, out_w4, n_rays);
}

// Round 3
// 76.389 us; speedup vs baseline: 1.1095x; 1.1095x over previous
//
#include <hip/hip_runtime.h>

#define BG_OPACITY 1.0e10f
#define EPS_RM 1e-6f

typedef float nfloat4 __attribute__((ext_vector_type(4)));

// Layout (all float32):
//   d_in[0] rays_densities : (BR, 64)      BR = B*R = 262144
//   d_in[1] rays_features  : (BR, 64, 3)
//   d_in[2] ray_lengths    : (BR, 64)
//   d_in[3] bg_color       : (1,)
// d_out = [features (BR,3) | depth (BR,1) | opacities (BR,1) | weights (BR,64)]
//
// SURFACE_THICKNESS=1 collapse: absorption = [EPS+exp(-S), 1, 1, ..., 1]
// with S = sum_j delta_j * relu(rho_j). Only the per-ray total is needed.
//
// Structure: 16 lanes/ray (4 samples each via float4), 4 rays/wave,
// 2 ray-groups (8 rays) per loop trip for ILP.

__device__ __forceinline__ void process_group(
    int ray, int q, size_t rbase, size_t fbase,
    const float4* __restrict__ dens4,
    const float4* __restrict__ feat4,
    const float4* __restrict__ len4,
    float bg,
    float* __restrict__ out_feat,
    float* __restrict__ out_depth,
    float* __restrict__ out_opac,
    nfloat4* __restrict__ out_w4,
    bool valid)
{
    float4 dv = dens4[rbase + q];
    float4 lv = len4[rbase + q];
    float4 f0 = feat4[fbase + 0];
    float4 f1 = feat4[fbase + 1];
    float4 f2 = feat4[fbase + 2];

    float nlen = __shfl_down(lv.x, 1);
    float d0 = lv.y - lv.x;
    float d1 = lv.z - lv.y;
    float d2 = lv.w - lv.z;
    float d3 = (q < 15) ? (nlen - lv.w) : BG_OPACITY;

    float w0 = d0 * fmaxf(dv.x, 0.f);
    float w1 = d1 * fmaxf(dv.y, 0.f);
    float w2 = d2 * fmaxf(dv.z, 0.f);
    float w3 = d3 * fmaxf(dv.w, 0.f);

    float S = (w0 + w1) + (w2 + w3);
    #pragma unroll
    for (int m = 1; m < 16; m <<= 1) S += __shfl_xor(S, m);

    float c0 = 1.f - __expf(-w0);
    float c1 = 1.f - __expf(-w1);
    float c2 = 1.f - __expf(-w2);
    float c3 = 1.f - __expf(-w3);
    if (q == 0) c0 *= (EPS_RM + __expf(-S));

    if (valid) {
        nfloat4 wv = {c0, c1, c2, c3};
        __builtin_nontemporal_store(wv, &out_w4[rbase + q]);
    }

    float fx = c0 * f0.x + c1 * f0.w + c2 * f1.z + c3 * f2.y;
    float fy = c0 * f0.y + c1 * f1.x + c2 * f1.w + c3 * f2.z;
    float fz = c0 * f0.z + c1 * f1.y + c2 * f2.x + c3 * f2.w;
    float dp = c0 * lv.x + c1 * lv.y + c2 * lv.z + c3 * lv.w;

    #pragma unroll
    for (int m = 1; m < 16; m <<= 1) {
        fx += __shfl_xor(fx, m);
        fy += __shfl_xor(fy, m);
        fz += __shfl_xor(fz, m);
        dp += __shfl_xor(dp, m);
    }

    if (q == 0 && valid) {
        float opac  = 1.f - __expf(-S);
        float addbg = (1.f - opac) * bg;
        out_feat[(size_t)ray * 3 + 0] = fx + addbg;
        out_feat[(size_t)ray * 3 + 1] = fy + addbg;
        out_feat[(size_t)ray * 3 + 2] = fz + addbg;
        out_depth[ray] = dp;
        out_opac[ray]  = opac;
    }
}

__global__ __launch_bounds__(256) void raymarch_kernel(
    const float4* __restrict__ dens4,
    const float4* __restrict__ feat4,
    const float4* __restrict__ len4,
    const float*  __restrict__ bgp,
    float*  __restrict__ out_feat,
    float*  __restrict__ out_depth,
    float*  __restrict__ out_opac,
    nfloat4* __restrict__ out_w4,
    int n_rays)
{
    const int lane   = threadIdx.x & 63;
    const int q      = lane & 15;
    const int rslot  = lane >> 4;
    const int wid    = (blockIdx.x * blockDim.x + threadIdx.x) >> 6;
    const int nwaves = (gridDim.x * blockDim.x) >> 6;
    const float bg   = bgp[0];

    const int ngroups = (n_rays + 3) >> 2;      // 4 rays per wave-group
    const int npairs  = (ngroups + 1) >> 1;     // 2 groups per loop trip

    for (int p = wid; p < npairs; p += nwaves) {
        const int g0 = p * 2;
        const int g1 = p * 2 + 1;

        int ray0 = g0 * 4 + rslot;
        int ray1 = g1 * 4 + rslot;
        bool v0 = ray0 < n_rays;
        bool v1 = (g1 < ((n_rays + 3) >> 2)) && (ray1 < n_rays);
        // clamp for safe (converged) loads; stores are predicated
        int r0c = v0 ? ray0 : (n_rays - 1);
        int r1c = v1 ? ray1 : (n_rays - 1);

        size_t rb0 = (size_t)r0c * 16, fb0 = (size_t)r0c * 48 + (size_t)q * 3;
        size_t rb1 = (size_t)r1c * 16, fb1 = (size_t)r1c * 48 + (size_t)q * 3;

        process_group(r0c, q, rb0, fb0, dens4, feat4, len4, bg,
                      out_feat, out_depth, out_opac, out_w4, v0);
        process_group(r1c, q, rb1, fb1, dens4, feat4, len4, bg,
                      out_feat, out_depth, out_opac, out_w4, v1);
    }
}

extern "C" void kernel_launch(void* const* d_in, const int* in_sizes, int n_in,
                              void* d_out, int out_size, void* d_ws, size_t ws_size,
                              hipStream_t stream) {
    const float4* dens4 = (const float4*)d_in[0];
    const float4* feat4 = (const float4*)d_in[1];
    const float4* len4  = (const float4*)d_in[2];
    const float*  bgp   = (const float*)d_in[3];

    const int n_rays = in_sizes[0] / 64;

    float* out = (float*)d_out;
    float*   out_feat  = out;
    float*   out_depth = out + (size_t)n_rays * 3;
    float*   out_opac  = out + (size_t)n_rays * 4;
    nfloat4* out_w4    = (nfloat4*)(out + (size_t)n_rays * 5);

    const int ngroups = (n_rays + 3) / 4;
    const int npairs  = (ngroups + 1) / 2;
    const int waves_per_block = 256 / 64;
    int blocks = (npairs + waves_per_block - 1) / waves_per_block;
    if (blocks > 2048) blocks = 2048;
    if (blocks < 1) blocks = 1;

    raymarch_kernel<<<blocks, 256, 0, stream>>>(
        dens4, feat4, len4, bgp,
        out_feat, out_depth, out_opac, out_w4, n_rays);
}